// Round 7
// baseline (186.054 us; speedup 1.0000x reference)
//
#include <hip/hip_runtime.h>
#include <hip/hip_bf16.h>
#include <math.h>

#define N_CLS 16384
#define DDIM  128
#define CSHIFT 50.0f    // fixed shift; exp(-ap) folded back in log domain at finalize
#define LOG2E 1.4426950408889634f
#define NEGC2 (-72.13475204444817f)   // -CSHIFT*LOG2E: acc = S*log2e - C*log2e via MFMA C-op

#if __has_builtin(__builtin_amdgcn_exp2f)
#define EXP2(x) __builtin_amdgcn_exp2f(x)
#else
#define EXP2(x) exp2f(x)
#endif

typedef __attribute__((ext_vector_type(8))) short short8;   // 8 bf16 (4 VGPRs)
typedef __attribute__((ext_vector_type(4))) float f32x4;    // MFMA accumulator

__device__ __forceinline__ unsigned short f2bf(float f) {
    __hip_bfloat16 h = __float2bfloat16(f);
    return *(unsigned short*)&h;
}

// ---------------------------------------------------------------------------
// Fragment-major layout for mfma_f32_16x16x32_bf16 operands:
//   X[row r][k] -> ((r>>4)*4 + (k>>5))*512 + (((k>>3)&3)*16 + (r&15))*8 + (k&7)
// one 16x16x32 fragment = 1024 contiguous bytes, lane-ordered (16 B/lane).
//
// prep: 8 pairs/block, 32 lanes/pair.
//   ap[i] = dot(x[2i], x[2i+1]) fp32 (pair {anchor,pos}={2i,2i+1}, dot symm)
//   Afrag = anchor rows * LOG2E (bf16, frag-major);  Bfrag = negative rows.
//   Zeroes out[0] (finalize atomicAdds into it).
// ---------------------------------------------------------------------------
__global__ __launch_bounds__(256)
void prep_kernel(const float* __restrict__ x,
                 const int* __restrict__ aidx,
                 float* __restrict__ ap,
                 unsigned short* __restrict__ Afrag,
                 unsigned short* __restrict__ Bfrag,
                 float* __restrict__ out) {
    const int t = threadIdx.x;
    const int l = t & 31;                       // lane in pair-group: k = l*4..l*4+3
    const int i = blockIdx.x * 8 + (t >> 5);    // class index
    const float4 xa = *(const float4*)(x + (2L * i) * DDIM + l * 4);
    const float4 xb = *(const float4*)(x + (2L * i + 1) * DDIM + l * 4);
    const float4 av = (aidx[i] == 0) ? xa : xb;

    const int kc = l >> 3, q = (l >> 1) & 3, j0 = (l & 1) * 4;
    const long base = ((long)((i >> 4) * 4 + kc)) * 512 + (q * 16 + (i & 15)) * 8 + j0;

    ushort4 a4;
    a4.x = f2bf(av.x * LOG2E); a4.y = f2bf(av.y * LOG2E);
    a4.z = f2bf(av.z * LOG2E); a4.w = f2bf(av.w * LOG2E);
    *(ushort4*)(Afrag + base) = a4;

    ushort4 b4;
    b4.x = f2bf(xb.x); b4.y = f2bf(xb.y); b4.z = f2bf(xb.z); b4.w = f2bf(xb.w);
    *(ushort4*)(Bfrag + base) = b4;

    float d = xa.x * xb.x + xa.y * xb.y + xa.z * xb.z + xa.w * xb.w;
    d += __shfl_xor(d, 1, 64);
    d += __shfl_xor(d, 2, 64);
    d += __shfl_xor(d, 4, 64);
    d += __shfl_xor(d, 8, 64);
    d += __shfl_xor(d, 16, 64);
    if (l == 0) ap[i] = d;
    if (blockIdx.x == 0 && t == 0) out[0] = 0.0f;
}

// ---------------------------------------------------------------------------
// fused: block = (row-tile rt = bid>>3, col-octant oct = bid&7, XCD-aligned).
// NO LDS, NO barriers. A frags in registers for the whole sweep; B streams
// from the L2-resident octant (kc ping-pong). TWO acc banks software-pipeline
// the tiles: MFMAs of tile t+1 interleave with the exp2/add epilogue of tile
// t (independent banks -> both pipes busy from one wave). kc=0 MFMA takes a
// persistent cinit as C operand, so acc needs no per-tile init.
// ---------------------------------------------------------------------------
__global__ __launch_bounds__(256, 2)
void fused_kernel(const unsigned short* __restrict__ Afrag,
                  const unsigned short* __restrict__ Bfrag,
                  float* __restrict__ partial) {
    const int tid = threadIdx.x;
    const int lane = tid & 63;
    const int w = tid >> 6;                 // wave 0..3
    const int quad = lane >> 4;             // 0..3
    const int l15 = lane & 15;              // 0..15
    const int oct = blockIdx.x & 7;         // XCD-aligned column octant
    const int rt = blockIdx.x >> 3;         // row tile 0..127
    const int wm2 = w >> 1;                 // wave row half
    const int wh = w & 1;                   // wave col half

    // hoist A fragments (rows rt*128 + wm2*64 + mt*16, all 4 kc)
    short8 af[4][4];
    {
        const unsigned short* abase =
            Afrag + ((long)(rt * 8 + wm2 * 4) * 4) * 512 + lane * 8;
        #pragma unroll
        for (int mt = 0; mt < 4; ++mt)
            #pragma unroll
            for (int kc = 0; kc < 4; ++kc)
                af[mt][kc] = *(const short8*)(abase + (mt * 4 + kc) * 512);
    }

    const unsigned short* bbase =
        Bfrag + ((long)(oct * 128 + wh * 4) * 4) * 512 + lane * 8;

    const f32x4 cinit = (f32x4){NEGC2, NEGC2, NEGC2, NEGC2};
    float rs[4][4] = {};
    short8 bA[4], bB[4];
    f32x4 accA[4][4], accB[4][4];

    #pragma unroll
    for (int nt = 0; nt < 4; ++nt)
        bA[nt] = *(const short8*)(bbase + nt * 4 * 512);

    // MFMA group for one col-tile into the given acc bank (kc ping-pong bA/bB)
    auto do_tile = [&](f32x4 (&acc)[4][4], int it) {
        const long itoff = (long)it * 16384;
        const long nxoff = (long)((it < 15) ? it + 1 : it) * 16384;
        // kc=0: consume bA, prefetch kc=1 -> bB; C operand = cinit (free init)
        #pragma unroll
        for (int nt = 0; nt < 4; ++nt)
            bB[nt] = *(const short8*)(bbase + itoff + (nt * 4 + 1) * 512);
        #pragma unroll
        for (int mt = 0; mt < 4; ++mt)
            #pragma unroll
            for (int nt = 0; nt < 4; ++nt)
                acc[mt][nt] = __builtin_amdgcn_mfma_f32_16x16x32_bf16(
                    af[mt][0], bA[nt], cinit, 0, 0, 0);
        // kc=1: consume bB, prefetch kc=2 -> bA
        #pragma unroll
        for (int nt = 0; nt < 4; ++nt)
            bA[nt] = *(const short8*)(bbase + itoff + (nt * 4 + 2) * 512);
        #pragma unroll
        for (int mt = 0; mt < 4; ++mt)
            #pragma unroll
            for (int nt = 0; nt < 4; ++nt)
                acc[mt][nt] = __builtin_amdgcn_mfma_f32_16x16x32_bf16(
                    af[mt][1], bB[nt], acc[mt][nt], 0, 0, 0);
        // kc=2: consume bA, prefetch kc=3 -> bB
        #pragma unroll
        for (int nt = 0; nt < 4; ++nt)
            bB[nt] = *(const short8*)(bbase + itoff + (nt * 4 + 3) * 512);
        #pragma unroll
        for (int mt = 0; mt < 4; ++mt)
            #pragma unroll
            for (int nt = 0; nt < 4; ++nt)
                acc[mt][nt] = __builtin_amdgcn_mfma_f32_16x16x32_bf16(
                    af[mt][2], bA[nt], acc[mt][nt], 0, 0, 0);
        // kc=3: consume bB, prefetch next tile kc=0 -> bA
        #pragma unroll
        for (int nt = 0; nt < 4; ++nt)
            bA[nt] = *(const short8*)(bbase + nxoff + nt * 4 * 512);
        #pragma unroll
        for (int mt = 0; mt < 4; ++mt)
            #pragma unroll
            for (int nt = 0; nt < 4; ++nt)
                acc[mt][nt] = __builtin_amdgcn_mfma_f32_16x16x32_bf16(
                    af[mt][3], bB[nt], acc[mt][nt], 0, 0, 0);
    };

    // epilogue: acc = S*log2e - C*log2e -> e = 2^acc = exp(S - C)
    auto do_epi = [&](f32x4 (&acc)[4][4], int it) {
        const int ct = oct * 16 + it;
        if (ct == rt) {
            #pragma unroll
            for (int mt = 0; mt < 4; ++mt)
                #pragma unroll
                for (int nt = 0; nt < 4; ++nt)
                    #pragma unroll
                    for (int reg = 0; reg < 4; ++reg) {
                        const bool diag = (wm2 == wh) && (mt == nt) &&
                                          (quad * 4 + reg == l15);
                        const float e = EXP2(acc[mt][nt][reg]);
                        rs[mt][reg] += diag ? 0.0f : e;
                    }
        } else {
            #pragma unroll
            for (int mt = 0; mt < 4; ++mt)
                #pragma unroll
                for (int nt = 0; nt < 4; ++nt)
                    #pragma unroll
                    for (int reg = 0; reg < 4; ++reg)
                        rs[mt][reg] += EXP2(acc[mt][nt][reg]);
        }
    };

    // software pipeline over 16 col-tiles, two acc banks
    do_tile(accA, 0);
    #pragma unroll
    for (int it = 1; it < 16; it += 2) {
        do_tile(accB, it);
        do_epi(accA, it - 1);
        if (it + 1 < 16) do_tile(accA, it + 1);
        do_epi(accB, it);
    }

    // cross-l15 reduce, plain store into slot (oct, col-half)
    const int slot = oct * 2 + wh;          // 16 slots
    const int rowBase = rt * 128 + wm2 * 64;
    #pragma unroll
    for (int mt = 0; mt < 4; ++mt)
        #pragma unroll
        for (int reg = 0; reg < 4; ++reg) {
            float v = rs[mt][reg];
            v += __shfl_xor(v, 1, 64);
            v += __shfl_xor(v, 2, 64);
            v += __shfl_xor(v, 4, 64);
            v += __shfl_xor(v, 8, 64);
            if (l15 == 0)
                partial[(long)slot * N_CLS + rowBase + mt * 16 + quad * 4 + reg] = v;
        }
}

// ---------------------------------------------------------------------------
// finalize: per row s = sum of 16 slot partials (= sum_j exp(S_ij - C), j!=i);
// loss = log1p(s * exp(C - ap)) via u = log(s) + C - ap; block-sum; atomicAdd.
// ---------------------------------------------------------------------------
__global__ __launch_bounds__(256)
void finalize_kernel(const float* __restrict__ partial,
                     const float* __restrict__ ap,
                     float* __restrict__ out) {
    __shared__ float red[256];
    const int t = threadIdx.x;
    const int row = blockIdx.x * 256 + t;
    float s = 0.0f;
    #pragma unroll
    for (int p = 0; p < 16; ++p) s += partial[(long)p * N_CLS + row];
    const float u = logf(s) + (CSHIFT - ap[row]);
    const float loss = (u > 25.0f) ? u : log1pf(__expf(u));
    red[t] = loss;
    __syncthreads();
    for (int st = 128; st > 0; st >>= 1) {
        if (t < st) red[t] += red[t + st];
        __syncthreads();
    }
    if (t == 0) atomicAdd(out, red[0]);
}

extern "C" void kernel_launch(void* const* d_in, const int* in_sizes, int n_in,
                              void* d_out, int out_size, void* d_ws, size_t ws_size,
                              hipStream_t stream) {
    const float* x    = (const float*)d_in[0];
    const int*   aidx = (const int*)d_in[1];
    // d_in[2] (pos_idx) derivable; unused.

    char* ws = (char*)d_ws;
    float* ap             = (float*)(ws);                                   // 64 KB
    float* partial        = (float*)(ws + 131072);                          // 1 MB
    unsigned short* Afrag = (unsigned short*)(ws + 131072 + 1048576);       // 4 MB
    unsigned short* Bfrag = (unsigned short*)(ws + 131072 + 1048576 + 4194304); // 4 MB

    prep_kernel<<<N_CLS / 8, 256, 0, stream>>>(x, aidx, ap, Afrag, Bfrag, (float*)d_out);
    fused_kernel<<<1024, 256, 0, stream>>>(Afrag, Bfrag, partial);
    finalize_kernel<<<64, 256, 0, stream>>>(partial, ap, (float*)d_out);
}

// Round 8
// 138.968 us; speedup vs baseline: 1.3388x; 1.3388x over previous
//
#include <hip/hip_runtime.h>
#include <hip/hip_bf16.h>
#include <math.h>

#define N_CLS 16384
#define DDIM  128
#define CSHIFT 50.0f    // fixed shift; exp(-ap) folded back in log domain at finalize
#define LOG2E 1.4426950408889634f
#define NEGC2 (-72.13475204444817f)   // -CSHIFT*LOG2E: acc = S*log2e - C*log2e via MFMA C-op

#if __has_builtin(__builtin_amdgcn_exp2f)
#define EXP2(x) __builtin_amdgcn_exp2f(x)
#else
#define EXP2(x) exp2f(x)
#endif

typedef __attribute__((ext_vector_type(8))) short short8;   // 8 bf16 (4 VGPRs)
typedef __attribute__((ext_vector_type(4))) float f32x4;    // MFMA accumulator

__device__ __forceinline__ unsigned short f2bf(float f) {
    __hip_bfloat16 h = __float2bfloat16(f);
    return *(unsigned short*)&h;
}

// ---------------------------------------------------------------------------
// Fragment-major layout for mfma_f32_16x16x32_bf16 operands:
//   X[row r][k] -> ((r>>4)*4 + (k>>5))*512 + (((k>>3)&3)*16 + (r&15))*8 + (k&7)
// one 16x16x32 fragment = 1024 contiguous bytes, lane-ordered (16 B/lane).
//
// prep: 8 pairs/block, 32 lanes/pair.
//   ap[i] = dot(x[2i], x[2i+1]) fp32 (pair {anchor,pos}={2i,2i+1}, dot symm)
//   Afrag = anchor rows * LOG2E (bf16, frag-major);  Bfrag = negative rows.
//   Zeroes out[0] (finalize atomicAdds into it).
// ---------------------------------------------------------------------------
__global__ __launch_bounds__(256)
void prep_kernel(const float* __restrict__ x,
                 const int* __restrict__ aidx,
                 float* __restrict__ ap,
                 unsigned short* __restrict__ Afrag,
                 unsigned short* __restrict__ Bfrag,
                 float* __restrict__ out) {
    const int t = threadIdx.x;
    const int l = t & 31;                       // lane in pair-group: k = l*4..l*4+3
    const int i = blockIdx.x * 8 + (t >> 5);    // class index
    const float4 xa = *(const float4*)(x + (2L * i) * DDIM + l * 4);
    const float4 xb = *(const float4*)(x + (2L * i + 1) * DDIM + l * 4);
    const float4 av = (aidx[i] == 0) ? xa : xb;

    const int kc = l >> 3, q = (l >> 1) & 3, j0 = (l & 1) * 4;
    const long base = ((long)((i >> 4) * 4 + kc)) * 512 + (q * 16 + (i & 15)) * 8 + j0;

    ushort4 a4;
    a4.x = f2bf(av.x * LOG2E); a4.y = f2bf(av.y * LOG2E);
    a4.z = f2bf(av.z * LOG2E); a4.w = f2bf(av.w * LOG2E);
    *(ushort4*)(Afrag + base) = a4;

    ushort4 b4;
    b4.x = f2bf(xb.x); b4.y = f2bf(xb.y); b4.z = f2bf(xb.z); b4.w = f2bf(xb.w);
    *(ushort4*)(Bfrag + base) = b4;

    float d = xa.x * xb.x + xa.y * xb.y + xa.z * xb.z + xa.w * xb.w;
    d += __shfl_xor(d, 1, 64);
    d += __shfl_xor(d, 2, 64);
    d += __shfl_xor(d, 4, 64);
    d += __shfl_xor(d, 8, 64);
    d += __shfl_xor(d, 16, 64);
    if (l == 0) ap[i] = d;
    if (blockIdx.x == 0 && t == 0) out[0] = 0.0f;
}

// ---------------------------------------------------------------------------
// fused: block = (row-tile rt = bid>>3, col-octant oct = bid&7, XCD-aligned).
// NO LDS, NO barriers. A frags in registers for the whole sweep; B streams
// from the L2-resident octant. Software pipeline at nt-column granularity:
// 64 stages of {16 MFMAs into bank X} overlapped with {16 exp2+add epilogue
// of bank Y from the previous stage}. Acc banks are 16 VGPRs each (not 64),
// so no spills (round-7 lesson: full double-banking spilled -> 70 MB scratch).
// kc=0 MFMA takes cinit as C operand -> zero-cost acc init.
// Diagonal: only stage it==rt-oct*16 in 1/8 of blocks runs the masked variant
// (diag must be EXCLUDED during accumulation -- it can dominate the row sum,
// so subtract-after would be absorbed; r5/r6 lesson).
// ---------------------------------------------------------------------------
__global__ __launch_bounds__(256, 2)
void fused_kernel(const unsigned short* __restrict__ Afrag,
                  const unsigned short* __restrict__ Bfrag,
                  float* __restrict__ partial) {
    const int tid = threadIdx.x;
    const int lane = tid & 63;
    const int w = tid >> 6;                 // wave 0..3
    const int quad = lane >> 4;             // 0..3
    const int l15 = lane & 15;              // 0..15
    const int oct = blockIdx.x & 7;         // XCD-aligned column octant
    const int rt = blockIdx.x >> 3;         // row tile 0..127
    const int wm2 = w >> 1;                 // wave row half
    const int wh = w & 1;                   // wave col half

    // hoist A fragments (rows rt*128 + wm2*64 + mt*16, all 4 kc)
    short8 af[4][4];
    {
        const unsigned short* abase =
            Afrag + ((long)(rt * 8 + wm2 * 4) * 4) * 512 + lane * 8;
        #pragma unroll
        for (int mt = 0; mt < 4; ++mt)
            #pragma unroll
            for (int kc = 0; kc < 4; ++kc)
                af[mt][kc] = *(const short8*)(abase + (mt * 4 + kc) * 512);
    }

    const unsigned short* bbase =
        Bfrag + ((long)(oct * 128 + wh * 4) * 4) * 512 + lane * 8;

    const f32x4 cinit = (f32x4){NEGC2, NEGC2, NEGC2, NEGC2};
    float rs[4][4] = {};
    short8 bP[4], bQ[4];
    f32x4 accA[4], accB[4];

    // diag stage: ct == rt possible only when rt>>4 == oct; then it = rt&15.
    const bool canDiag = ((rt >> 4) == oct) && (wm2 == wh);
    const int itd = canDiag ? (rt & 15) : -1;

    auto mfma4 = [&](f32x4 (&acc)[4], short8 (&b)[4]) {
        #pragma unroll
        for (int mt = 0; mt < 4; ++mt)
            acc[mt] = __builtin_amdgcn_mfma_f32_16x16x32_bf16(
                af[mt][0], b[0], cinit, 0, 0, 0);
        #pragma unroll
        for (int kc = 1; kc < 4; ++kc)
            #pragma unroll
            for (int mt = 0; mt < 4; ++mt)
                acc[mt] = __builtin_amdgcn_mfma_f32_16x16x32_bf16(
                    af[mt][kc], b[kc], acc[mt], 0, 0, 0);
    };
    auto epi = [&](f32x4 (&acc)[4]) {
        #pragma unroll
        for (int mt = 0; mt < 4; ++mt)
            #pragma unroll
            for (int reg = 0; reg < 4; ++reg)
                rs[mt][reg] += EXP2(acc[mt][reg]);
    };
    auto epiD = [&](f32x4 (&acc)[4], int nt) {
        #pragma unroll
        for (int mt = 0; mt < 4; ++mt)
            #pragma unroll
            for (int reg = 0; reg < 4; ++reg) {
                float e = EXP2(acc[mt][reg]);
                if (mt == nt) e = (quad * 4 + reg == l15) ? 0.0f : e;
                rs[mt][reg] += e;
            }
    };

    // preload b for stage (it=0, nt=0)
    #pragma unroll
    for (int kc = 0; kc < 4; ++kc)
        bP[kc] = *(const short8*)(bbase + kc * 512);

    bool dprev = false;
    for (int it = 0; it < 16; ++it) {
        const unsigned short* p1 = bbase + (long)it * 16384;
        const bool d = (it == itd);

        // stage nt=0: acc A <- bP ; prefetch (it,1) -> bQ ; epi stage (it-1,3)
        #pragma unroll
        for (int kc = 0; kc < 4; ++kc)
            bQ[kc] = *(const short8*)(p1 + 2048 + kc * 512);
        mfma4(accA, bP);
        if (it > 0) { if (dprev) epiD(accB, 3); else epi(accB); }

        // stage nt=1: acc B <- bQ ; prefetch (it,2) -> bP ; epi stage (it,0)
        #pragma unroll
        for (int kc = 0; kc < 4; ++kc)
            bP[kc] = *(const short8*)(p1 + 4096 + kc * 512);
        mfma4(accB, bQ);
        if (d) epiD(accA, 0); else epi(accA);

        // stage nt=2: acc A <- bP ; prefetch (it,3) -> bQ ; epi stage (it,1)
        #pragma unroll
        for (int kc = 0; kc < 4; ++kc)
            bQ[kc] = *(const short8*)(p1 + 6144 + kc * 512);
        mfma4(accA, bP);
        if (d) epiD(accB, 1); else epi(accB);

        // stage nt=3: acc B <- bQ ; prefetch (it+1,0) -> bP ; epi stage (it,2)
        const unsigned short* p2 = bbase + (long)((it < 15) ? it + 1 : it) * 16384;
        #pragma unroll
        for (int kc = 0; kc < 4; ++kc)
            bP[kc] = *(const short8*)(p2 + kc * 512);
        mfma4(accB, bQ);
        if (d) epiD(accA, 2); else epi(accA);

        dprev = d;
    }
    // drain: epi of stage (15,3)
    if (dprev) epiD(accB, 3); else epi(accB);

    // cross-l15 reduce, plain store into slot (oct, col-half)
    const int slot = oct * 2 + wh;          // 16 slots
    const int rowBase = rt * 128 + wm2 * 64;
    #pragma unroll
    for (int mt = 0; mt < 4; ++mt)
        #pragma unroll
        for (int reg = 0; reg < 4; ++reg) {
            float v = rs[mt][reg];
            v += __shfl_xor(v, 1, 64);
            v += __shfl_xor(v, 2, 64);
            v += __shfl_xor(v, 4, 64);
            v += __shfl_xor(v, 8, 64);
            if (l15 == 0)
                partial[(long)slot * N_CLS + rowBase + mt * 16 + quad * 4 + reg] = v;
        }
}

// ---------------------------------------------------------------------------
// finalize: per row s = sum of 16 slot partials (= sum_j exp(S_ij - C), j!=i);
// loss = log1p(s * exp(C - ap)) via u = log(s) + C - ap; block-sum; atomicAdd.
// ---------------------------------------------------------------------------
__global__ __launch_bounds__(256)
void finalize_kernel(const float* __restrict__ partial,
                     const float* __restrict__ ap,
                     float* __restrict__ out) {
    __shared__ float red[256];
    const int t = threadIdx.x;
    const int row = blockIdx.x * 256 + t;
    float s = 0.0f;
    #pragma unroll
    for (int p = 0; p < 16; ++p) s += partial[(long)p * N_CLS + row];
    const float u = logf(s) + (CSHIFT - ap[row]);
    const float loss = (u > 25.0f) ? u : log1pf(__expf(u));
    red[t] = loss;
    __syncthreads();
    for (int st = 128; st > 0; st >>= 1) {
        if (t < st) red[t] += red[t + st];
        __syncthreads();
    }
    if (t == 0) atomicAdd(out, red[0]);
}

extern "C" void kernel_launch(void* const* d_in, const int* in_sizes, int n_in,
                              void* d_out, int out_size, void* d_ws, size_t ws_size,
                              hipStream_t stream) {
    const float* x    = (const float*)d_in[0];
    const int*   aidx = (const int*)d_in[1];
    // d_in[2] (pos_idx) derivable; unused.

    char* ws = (char*)d_ws;
    float* ap             = (float*)(ws);                                   // 64 KB
    float* partial        = (float*)(ws + 131072);                          // 1 MB
    unsigned short* Afrag = (unsigned short*)(ws + 131072 + 1048576);       // 4 MB
    unsigned short* Bfrag = (unsigned short*)(ws + 131072 + 1048576 + 4194304); // 4 MB

    prep_kernel<<<N_CLS / 8, 256, 0, stream>>>(x, aidx, ap, Afrag, Bfrag, (float*)d_out);
    fused_kernel<<<1024, 256, 0, stream>>>(Afrag, Bfrag, partial);
    finalize_kernel<<<64, 256, 0, stream>>>(partial, ap, (float*)d_out);
}